// Round 6
// baseline (741.402 us; speedup 1.0000x reference)
//
#include <hip/hip_runtime.h>
#include <math.h>

#define NN 50000
#define EE 800000
#define FIN 96
#define FHID 384
#define FOUT 192
#define BN_EPS 1e-5f
#define NBUCKET 391          // ceil(NN/128), bucket = row >> 7
#define NCHUNK 391           // ceil(EE/2048), 2048 edges per workgroup

typedef short  short4v  __attribute__((ext_vector_type(4)));
typedef short  short8v  __attribute__((ext_vector_type(8)));
typedef float  f32x4    __attribute__((ext_vector_type(4)));

__device__ __forceinline__ unsigned short f2b(float f) {   // fp32 -> bf16 RNE
    unsigned u = __float_as_uint(f);
    unsigned r = u + 0x7FFFu + ((u >> 16) & 1u);
    return (unsigned short)(r >> 16);
}
__device__ __forceinline__ float b2f(unsigned short s) {
    return __uint_as_float((unsigned)s << 16);
}

// ---------------- prep: weights bf16+transpose ----------------------------
__global__ __launch_bounds__(256) void prep_w_kernel(
    const float* __restrict__ W1, const float* __restrict__ W2,
    unsigned short* __restrict__ W1T, unsigned short* __restrict__ W2T)
{
    int i = blockIdx.x * 256 + threadIdx.x;
    if (i < FHID * FIN) {                   // W1T[n][k] = W1[k][n]
        int n = i / FIN, k = i - n * FIN;
        W1T[i] = f2b(W1[(size_t)k * FHID + n]);
    }
    int j = i - FHID * FIN;
    if (j >= 0 && j < FOUT * FHID) {        // W2T[n][k] = W2[k][n]
        int n = j / FHID, k = j - n * FHID;
        W2T[j] = f2b(W2[(size_t)k * FOUT + n]);
    }
}

// ---------------- prep: x -> bf16 ----------------------------------------
__global__ __launch_bounds__(256) void prep_x_kernel(
    const float* __restrict__ x, unsigned short* __restrict__ xb)
{
    int i4 = blockIdx.x * 256 + threadIdx.x;
    if (i4 >= NN * FIN / 4) return;
    float4 v = *(const float4*)(x + (size_t)i4 * 4);
    short4v s;
    s.x = f2b(v.x); s.y = f2b(v.y); s.z = f2b(v.z); s.w = f2b(v.w);
    *(short4v*)(xb + (size_t)i4 * 4) = s;
}

// ---------------- bucket histogram (LDS-chunked) --------------------------
__global__ __launch_bounds__(256) void bucket_hist_kernel(
    const int* __restrict__ row, int* __restrict__ bcnt)
{
    __shared__ int lh[NBUCKET];
    int tid = threadIdx.x;
    for (int i = tid; i < NBUCKET; i += 256) lh[i] = 0;
    __syncthreads();
    int base = blockIdx.x * 2048;
    #pragma unroll
    for (int j = 0; j < 8; ++j) {
        int e = base + j * 256 + tid;
        if (e < EE) atomicAdd(&lh[row[e] >> 7], 1);
    }
    __syncthreads();
    for (int i = tid; i < NBUCKET; i += 256)
        if (lh[i]) atomicAdd(&bcnt[i], lh[i]);
}

// ---------------- bucket scan (1 block) -----------------------------------
__global__ __launch_bounds__(512) void bucket_scan_kernel(
    const int* __restrict__ bcnt, int* __restrict__ bofs, int* __restrict__ cursor)
{
    __shared__ int s[512];
    int t = threadIdx.x;
    int v = (t < NBUCKET) ? bcnt[t] : 0;
    s[t] = v;
    __syncthreads();
    for (int o = 1; o < 512; o <<= 1) {
        int add = (t >= o) ? s[t - o] : 0;
        __syncthreads();
        s[t] += add;
        __syncthreads();
    }
    if (t < NBUCKET) {
        int excl = s[t] - v;
        bofs[t] = excl;
        cursor[t] = excl;
        if (t == NBUCKET - 1) bofs[NBUCKET] = s[t];
    }
}

// ---------------- binned counting-sort scatter ----------------------------
// Edges grouped by bucket; each wg writes its per-bucket runs contiguously.
__global__ __launch_bounds__(256) void bucket_bin_kernel(
    const int* __restrict__ row, const int* __restrict__ col,
    const float* __restrict__ val, int* __restrict__ cursor,
    int2* __restrict__ ebin)
{
    __shared__ int lh[NBUCKET];
    __shared__ int lg[NBUCKET];
    int tid = threadIdx.x;
    for (int i = tid; i < NBUCKET; i += 256) lh[i] = 0;
    __syncthreads();
    int base = blockIdx.x * 2048;
    int eb[8], er[8], ec[8], ev[8];
    #pragma unroll
    for (int j = 0; j < 8; ++j) {
        int e = base + j * 256 + tid;
        eb[j] = -1;
        if (e < EE) {
            int r = row[e];
            int b = r >> 7;
            eb[j] = b;
            er[j] = atomicAdd(&lh[b], 1);              // local rank
            ec[j] = col[e] | ((r & 127) << 17);        // col(17b) | rowlocal(7b)
            ev[j] = __float_as_int(val[e]);
        }
    }
    __syncthreads();
    for (int i = tid; i < NBUCKET; i += 256)
        if (lh[i]) lg[i] = atomicAdd(&cursor[i], lh[i]);
    __syncthreads();
    #pragma unroll
    for (int j = 0; j < 8; ++j) {
        if (eb[j] >= 0)
            ebin[lg[eb[j]] + er[j]] = make_int2(ec[j], ev[j]);
    }
}

// ---------------- per-bucket aggregation (LDS atomics) --------------------
// wg b owns rows [128b, 128b+128): agg = sum val*xb[col] + eps*xb[self].
__global__ __launch_bounds__(256) void bucket_agg_kernel(
    const unsigned short* __restrict__ xb, const int* __restrict__ bofs,
    const int2* __restrict__ ebin, const float* __restrict__ epsp,
    unsigned short* __restrict__ aggb)
{
    __shared__ float agg[128 * 97];     // stride 97: spread row-base banks
    int tid = threadIdx.x;
    int b = blockIdx.x;
    for (int i = tid; i < 128 * 97; i += 256) agg[i] = 0.f;
    __syncthreads();
    int beg = bofs[b], end = bofs[b + 1];
    int g = tid >> 5, lane = tid & 31;
    for (int e = beg + g; e < end; e += 8) {
        int2 ed = ebin[e];
        int c = ed.x & 0x1FFFF;
        int rl = ed.x >> 17;
        float v = __int_as_float(ed.y);
        const unsigned short* xr = xb + (size_t)c * FIN;
        atomicAdd(&agg[rl * 97 + lane],      v * b2f(xr[lane]));
        atomicAdd(&agg[rl * 97 + lane + 32], v * b2f(xr[lane + 32]));
        atomicAdd(&agg[rl * 97 + lane + 64], v * b2f(xr[lane + 64]));
    }
    __syncthreads();
    float eps = epsp[0];
    int flatbase = b * 128 * FIN;       // aggb/xb are dense [N][96]
    for (int i4 = tid; i4 < 128 * FIN / 4; i4 += 256) {
        int flat = i4 * 4;
        if (flatbase + flat >= NN * FIN) break;
        int r = flat / FIN, c = flat - r * FIN;
        short4v xv = *(const short4v*)(xb + flatbase + flat);
        short4v o;
        o.x = f2b(agg[r * 97 + c]     + eps * b2f((unsigned short)xv.x));
        o.y = f2b(agg[r * 97 + c + 1] + eps * b2f((unsigned short)xv.y));
        o.z = f2b(agg[r * 97 + c + 2] + eps * b2f((unsigned short)xv.z));
        o.w = f2b(agg[r * 97 + c + 3] + eps * b2f((unsigned short)xv.w));
        *(short4v*)(aggb + flatbase + flat) = o;
    }
}

// ---------------- GEMM1 (MFMA): h1 = agg @ W1 + b1, bf16 out + stats -----
__global__ __launch_bounds__(256) void gemm1_mfma_kernel(
    const unsigned short* __restrict__ aggb, const unsigned short* __restrict__ W1T,
    const float* __restrict__ b1,
    unsigned short* __restrict__ h1, float* __restrict__ sum1,
    float* __restrict__ sq1)
{
    __shared__ short As[128 * 104];   // [m][k] bf16
    __shared__ short Bs[128 * 104];   // [n][k] bf16
    int tid = threadIdx.x;
    int m0 = blockIdx.x * 128;
    int n0 = blockIdx.y * 128;
    int lane = tid & 63;
    int w = tid >> 6, wr = w >> 1, wc = w & 1;
    int l15 = lane & 15, lk = (lane >> 4) * 8;

    for (int i8 = tid; i8 < 128 * 12; i8 += 256) {
        int m = i8 / 12;
        int k8 = (i8 - m * 12) * 8;
        int gm = m0 + m;
        short8v v = (short8v)(short)0;
        if (gm < NN) v = *(const short8v*)(aggb + (size_t)gm * FIN + k8);
        *(short8v*)&As[m * 104 + k8] = v;
    }
    for (int i8 = tid; i8 < 128 * 12; i8 += 256) {
        int n = i8 / 12;
        int k8 = (i8 - n * 12) * 8;
        *(short8v*)&Bs[n * 104 + k8] =
            *(const short8v*)(W1T + (size_t)(n0 + n) * FIN + k8);
    }
    __syncthreads();

    f32x4 acc[4][4];
    #pragma unroll
    for (int a = 0; a < 4; ++a)
        #pragma unroll
        for (int b = 0; b < 4; ++b) acc[a][b] = (f32x4)(0.f);

    #pragma unroll
    for (int ks = 0; ks < 3; ++ks) {
        int k0 = ks * 32;
        short8v af[4], bf[4];
        #pragma unroll
        for (int f = 0; f < 4; ++f)
            af[f] = *(short8v*)&As[(wr*64 + f*16 + l15) * 104 + k0 + lk];
        #pragma unroll
        for (int f = 0; f < 4; ++f)
            bf[f] = *(short8v*)&Bs[(wc*64 + f*16 + l15) * 104 + k0 + lk];
        #pragma unroll
        for (int fm = 0; fm < 4; ++fm)
            #pragma unroll
            for (int fn = 0; fn < 4; ++fn)
                acc[fm][fn] = __builtin_amdgcn_mfma_f32_16x16x32_bf16(
                    af[fm], bf[fn], acc[fm][fn], 0, 0, 0);
    }

    float bias[4], cs[4], cq[4];
    #pragma unroll
    for (int fn = 0; fn < 4; ++fn) {
        bias[fn] = b1[n0 + wc*64 + fn*16 + l15];
        cs[fn] = 0.f; cq[fn] = 0.f;
    }
    #pragma unroll
    for (int fm = 0; fm < 4; ++fm) {
        int mb = m0 + wr*64 + fm*16 + (lane >> 4) * 4;
        #pragma unroll
        for (int r = 0; r < 4; ++r) {
            int gm = mb + r;
            if (gm < NN) {
                #pragma unroll
                for (int fn = 0; fn < 4; ++fn) {
                    float h = acc[fm][fn][r] + bias[fn];
                    cs[fn] += h; cq[fn] += h * h;
                    h1[(size_t)gm * FHID + n0 + wc*64 + fn*16 + l15] = f2b(h);
                }
            }
        }
    }
    #pragma unroll
    for (int fn = 0; fn < 4; ++fn) {
        cs[fn] += __shfl_xor(cs[fn], 16); cs[fn] += __shfl_xor(cs[fn], 32);
        cq[fn] += __shfl_xor(cq[fn], 16); cq[fn] += __shfl_xor(cq[fn], 32);
    }
    __syncthreads();
    float* sS = (float*)As;
    if (lane < 16) {
        #pragma unroll
        for (int fn = 0; fn < 4; ++fn) {
            sS[w * 64 + fn * 16 + l15]       = cs[fn];
            sS[256 + w * 64 + fn * 16 + l15] = cq[fn];
        }
    }
    __syncthreads();
    if (tid < 128) {
        float s = sS[tid] + sS[tid + 128];
        float q = sS[256 + tid] + sS[256 + tid + 128];
        atomicAdd(sum1 + n0 + tid, s);
        atomicAdd(sq1 + n0 + tid, q);
    }
}

// ---- fold BN stats into scale/shift --------------------------------------
__global__ __launch_bounds__(256) void bnparam_kernel(
    const float* __restrict__ sum, const float* __restrict__ sq,
    const float* __restrict__ g, const float* __restrict__ be,
    float* __restrict__ scale, float* __restrict__ shift, int F)
{
    int i = blockIdx.x * 256 + threadIdx.x;
    if (i >= F) return;
    float mean = sum[i] * (1.f / NN);
    float var  = sq[i] * (1.f / NN) - mean * mean;
    float s = g[i] * rsqrtf(var + BN_EPS);
    scale[i] = s;
    shift[i] = be[i] - mean * s;
}

// ---------------- GEMM2 (MFMA): out = elu(bn1(h1)) @ W2 + b2, + stats ----
#define G2_LDA 72
#define G2_LDB 72
__global__ __launch_bounds__(256) void gemm2_mfma_kernel(
    const unsigned short* __restrict__ h1, const unsigned short* __restrict__ W2T,
    const float* __restrict__ b2,
    const float* __restrict__ scale1, const float* __restrict__ shift1,
    float* __restrict__ out, float* __restrict__ sum2, float* __restrict__ sq2)
{
    __shared__ short As[64 * G2_LDA];
    __shared__ short Bs[192 * G2_LDB];
    __shared__ float sc[FHID], sh[FHID];
    int tid = threadIdx.x;
    int m0 = blockIdx.x * 64;
    int lane = tid & 63;
    int w = tid >> 6, wr = w >> 1, wc = w & 1;
    int l15 = lane & 15, lk = (lane >> 4) * 8;

    for (int i = tid; i < FHID; i += 256) { sc[i] = scale1[i]; sh[i] = shift1[i]; }

    short8v pa[2], pb[6];

    auto LOAD = [&](int k0) {
        #pragma unroll
        for (int l = 0; l < 2; ++l) {
            int idx = tid + l * 256;
            int am = idx >> 3, k8 = (idx & 7) * 8;
            int gm = m0 + am;
            pa[l] = (gm < NN)
                ? *(const short8v*)(h1 + (size_t)gm * FHID + k0 + k8)
                : (short8v)(short)0;
        }
        #pragma unroll
        for (int l = 0; l < 6; ++l) {
            int idx = tid + l * 256;
            int bn = idx >> 3, k8 = (idx & 7) * 8;
            pb[l] = *(const short8v*)(W2T + (size_t)bn * FHID + k0 + k8);
        }
    };
    auto WRITE = [&](int k0) {
        #pragma unroll
        for (int l = 0; l < 2; ++l) {
            int idx = tid + l * 256;
            int am = idx >> 3, k8 = (idx & 7) * 8;
            short8v v;
            #pragma unroll
            for (int j = 0; j < 8; ++j) {
                int k = k0 + k8 + j;
                float t = sc[k] * b2f((unsigned short)pa[l][j]) + sh[k];
                float e = t > 0.f ? t : __expf(t) - 1.f;
                v[j] = (short)f2b(e);
            }
            *(short8v*)&As[am * G2_LDA + k8] = v;
        }
        #pragma unroll
        for (int l = 0; l < 6; ++l) {
            int idx = tid + l * 256;
            int bn = idx >> 3, k8 = (idx & 7) * 8;
            *(short8v*)&Bs[bn * G2_LDB + k8] = pb[l];
        }
    };

    f32x4 acc[2][6];
    #pragma unroll
    for (int a = 0; a < 2; ++a)
        #pragma unroll
        for (int b = 0; b < 6; ++b) acc[a][b] = (f32x4)(0.f);

    LOAD(0);
    __syncthreads();
    WRITE(0);
    __syncthreads();

    for (int t = 0; t < 6; ++t) {
        if (t < 5) LOAD((t + 1) * 64);
        #pragma unroll
        for (int ks = 0; ks < 2; ++ks) {
            short8v af[2], bf[6];
            #pragma unroll
            for (int f = 0; f < 2; ++f)
                af[f] = *(short8v*)&As[(wr*32 + f*16 + l15) * G2_LDA + ks*32 + lk];
            #pragma unroll
            for (int g = 0; g < 6; ++g)
                bf[g] = *(short8v*)&Bs[(wc*96 + g*16 + l15) * G2_LDB + ks*32 + lk];
            #pragma unroll
            for (int fm = 0; fm < 2; ++fm)
                #pragma unroll
                for (int fn = 0; fn < 6; ++fn)
                    acc[fm][fn] = __builtin_amdgcn_mfma_f32_16x16x32_bf16(
                        af[fm], bf[fn], acc[fm][fn], 0, 0, 0);
        }
        __syncthreads();
        if (t < 5) {
            WRITE((t + 1) * 64);
            __syncthreads();
        }
    }

    float bias[6], cs[6], cq[6];
    #pragma unroll
    for (int fn = 0; fn < 6; ++fn) {
        bias[fn] = b2[wc*96 + fn*16 + l15];
        cs[fn] = 0.f; cq[fn] = 0.f;
    }
    #pragma unroll
    for (int fm = 0; fm < 2; ++fm) {
        int mb = m0 + wr*32 + fm*16 + (lane >> 4) * 4;
        #pragma unroll
        for (int r = 0; r < 4; ++r) {
            int gm = mb + r;
            if (gm < NN) {
                #pragma unroll
                for (int fn = 0; fn < 6; ++fn) {
                    float v = acc[fm][fn][r] + bias[fn];
                    cs[fn] += v; cq[fn] += v * v;
                    out[(size_t)gm * FOUT + wc*96 + fn*16 + l15] = v;
                }
            }
        }
    }
    #pragma unroll
    for (int fn = 0; fn < 6; ++fn) {
        cs[fn] += __shfl_xor(cs[fn], 16); cs[fn] += __shfl_xor(cs[fn], 32);
        cq[fn] += __shfl_xor(cq[fn], 16); cq[fn] += __shfl_xor(cq[fn], 32);
    }
    __syncthreads();
    float* sS = (float*)As;
    if (lane < 16) {
        #pragma unroll
        for (int fn = 0; fn < 6; ++fn) {
            sS[w * 96 + fn * 16 + l15]       = cs[fn];
            sS[384 + w * 96 + fn * 16 + l15] = cq[fn];
        }
    }
    __syncthreads();
    if (tid < 192) {
        float s = sS[tid] + sS[192 + tid];
        float q = sS[384 + tid] + sS[384 + 192 + tid];
        atomicAdd(sum2 + tid, s);
        atomicAdd(sq2 + tid, q);
    }
}

// ---------------- BN2 + ELU, in-place ------------------------------------
__global__ __launch_bounds__(256) void bn2_elu_kernel(
    float* __restrict__ out, const float* __restrict__ scale2,
    const float* __restrict__ shift2)
{
    int gid = blockIdx.x * 256 + threadIdx.x;
    if (gid >= NN * FOUT / 4) return;
    size_t base = (size_t)gid * 4;
    int c0 = (int)(base % FOUT);
    float4 h = *(float4*)(out + base);
    float hv[4] = {h.x, h.y, h.z, h.w};
    float rv[4];
    #pragma unroll
    for (int j = 0; j < 4; ++j) {
        float t = scale2[c0 + j] * hv[j] + shift2[c0 + j];
        rv[j] = t > 0.f ? t : __expf(t) - 1.f;
    }
    *(float4*)(out + base) = make_float4(rv[0], rv[1], rv[2], rv[3]);
}

__global__ __launch_bounds__(256) void zero_out_kernel(float* out, int n) {
    int gid = blockIdx.x * 256 + threadIdx.x;
    if (gid < n) out[gid] = 0.f;
}

extern "C" void kernel_launch(void* const* d_in, const int* in_sizes, int n_in,
                              void* d_out, int out_size, void* d_ws, size_t ws_size,
                              hipStream_t stream) {
    const float* x    = (const float*)d_in[0];
    const float* val  = (const float*)d_in[1];
    const float* W1   = (const float*)d_in[2];
    const float* b1   = (const float*)d_in[3];
    const float* g1   = (const float*)d_in[4];
    const float* be1  = (const float*)d_in[5];
    const float* W2   = (const float*)d_in[6];
    const float* b2   = (const float*)d_in[7];
    const float* g2   = (const float*)d_in[8];
    const float* be2  = (const float*)d_in[9];
    const float* epsp = (const float*)d_in[10];
    const int* row    = (const int*)d_in[11];
    const int* col    = (const int*)d_in[12];
    float* out = (float*)d_out;

    // ws layout (float idx):
    //       0 sum1[384] | 384 sq1[384] | 768 sum2[192] | 960 sq2[192]
    //    1152 scale1[384] | 1536 shift1[384] | 1920 scale2[192] | 2112 shift2[192]
    //    2304 bcnt int[391] | 2695 bofs int[392] | 3087 cursor int[391] | pad
    //    3584 W1T ushort[36864]  (18432 f)
    //   22016 W2T ushort[73728]  (36864 f)
    //   58880 xb  ushort[4.8M]   (2.4M f)
    // 2458880 aggb ushort[4.8M]  (2.4M f)
    // 4858880 h1 bf16[19.2M]     (9.6M f); ebin int2[800K] aliases h1
    //         (ebin dead before gemm1 writes h1) -> need 14458880 f = 57.8 MB
    const size_t need = (size_t)14458880 * sizeof(float);
    if (ws_size < need) {
        zero_out_kernel<<<(out_size + 255) / 256, 256, 0, stream>>>(out, out_size);
        return;
    }
    float* ws     = (float*)d_ws;
    float* sum1   = ws;
    float* sq1    = ws + 384;
    float* sum2   = ws + 768;
    float* sq2    = ws + 960;
    float* scale1 = ws + 1152;
    float* shift1 = ws + 1536;
    float* scale2 = ws + 1920;
    float* shift2 = ws + 2112;
    int*   bcnt   = (int*)(ws + 2304);
    int*   bofs   = (int*)(ws + 2695);
    int*   cursor = (int*)(ws + 3087);
    unsigned short* W1T  = (unsigned short*)(ws + 3584);
    unsigned short* W2T  = (unsigned short*)(ws + 22016);
    unsigned short* xb   = (unsigned short*)(ws + 58880);
    unsigned short* aggb = (unsigned short*)(ws + 2458880);
    unsigned short* h1   = (unsigned short*)(ws + 4858880);
    int2*  ebin   = (int2*)(ws + 4858880);          // alias h1 (dead early)

    // zero stats + bucket counters (14 KB)
    hipMemsetAsync(d_ws, 0, 3584 * sizeof(float), stream);

    prep_w_kernel<<<(FHID*FIN + FOUT*FHID + 255) / 256, 256, 0, stream>>>(
        W1, W2, W1T, W2T);
    prep_x_kernel<<<(NN * FIN / 4 + 255) / 256, 256, 0, stream>>>(x, xb);

    bucket_hist_kernel<<<NCHUNK, 256, 0, stream>>>(row, bcnt);
    bucket_scan_kernel<<<1, 512, 0, stream>>>(bcnt, bofs, cursor);
    bucket_bin_kernel<<<NCHUNK, 256, 0, stream>>>(row, col, val, cursor, ebin);
    bucket_agg_kernel<<<NBUCKET, 256, 0, stream>>>(xb, bofs, ebin, epsp, aggb);

    dim3 grid1((NN + 127) / 128, 3, 1);
    gemm1_mfma_kernel<<<grid1, 256, 0, stream>>>(aggb, W1T, b1, h1, sum1, sq1);
    bnparam_kernel<<<2, 256, 0, stream>>>(sum1, sq1, g1, be1, scale1, shift1, FHID);

    gemm2_mfma_kernel<<<(NN + 63) / 64, 256, 0, stream>>>(
        h1, W2T, b2, scale1, shift1, out, sum2, sq2);
    bnparam_kernel<<<1, 256, 0, stream>>>(sum2, sq2, g2, be2, scale2, shift2, FOUT);

    bn2_elu_kernel<<<(NN * FOUT / 4 + 255) / 256, 256, 0, stream>>>(
        out, scale2, shift2);
}

// Round 7
// 294.333 us; speedup vs baseline: 2.5189x; 2.5189x over previous
//
#include <hip/hip_runtime.h>
#include <math.h>

#define NN 50000
#define EE 800000
#define FIN 96
#define FHID 384
#define FOUT 192
#define BN_EPS 1e-5f
#define NBLK_SCAN 196   // ceil(NN/256)
#define NBUCKET 391     // ceil(NN/128), bucket = row >> 7
#define NCHUNK 391      // ceil(EE/2048)

typedef short  short4v  __attribute__((ext_vector_type(4)));
typedef short  short8v  __attribute__((ext_vector_type(8)));
typedef float  f32x4    __attribute__((ext_vector_type(4)));

__device__ __forceinline__ unsigned short f2b(float f) {   // fp32 -> bf16 RNE
    unsigned u = __float_as_uint(f);
    unsigned r = u + 0x7FFFu + ((u >> 16) & 1u);
    return (unsigned short)(r >> 16);
}
__device__ __forceinline__ float b2f(unsigned short s) {
    return __uint_as_float((unsigned)s << 16);
}

// ---------------- prep: weights bf16+transpose ----------------------------
__global__ __launch_bounds__(256) void prep_w_kernel(
    const float* __restrict__ W1, const float* __restrict__ W2,
    unsigned short* __restrict__ W1T, unsigned short* __restrict__ W2T)
{
    int i = blockIdx.x * 256 + threadIdx.x;
    if (i < FHID * FIN) {                   // W1T[n][k] = W1[k][n]
        int n = i / FIN, k = i - n * FIN;
        W1T[i] = f2b(W1[(size_t)k * FHID + n]);
    }
    int j = i - FHID * FIN;
    if (j >= 0 && j < FOUT * FHID) {        // W2T[n][k] = W2[k][n]
        int n = j / FHID, k = j - n * FHID;
        W2T[j] = f2b(W2[(size_t)k * FOUT + n]);
    }
}

// ---------------- prep: x -> bf16 ----------------------------------------
__global__ __launch_bounds__(256) void prep_x_kernel(
    const float* __restrict__ x, unsigned short* __restrict__ xb)
{
    int i4 = blockIdx.x * 256 + threadIdx.x;
    if (i4 >= NN * FIN / 4) return;
    float4 v = *(const float4*)(x + (size_t)i4 * 4);
    short4v s;
    s.x = f2b(v.x); s.y = f2b(v.y); s.z = f2b(v.z); s.w = f2b(v.w);
    *(short4v*)(xb + (size_t)i4 * 4) = s;
}

// ---------------- row-level CSR: hist + scan ------------------------------
__global__ __launch_bounds__(256) void hist_kernel(
    const int* __restrict__ row, int* __restrict__ deg)
{
    int i = blockIdx.x * 256 + threadIdx.x;
    if (i < EE) atomicAdd(&deg[row[i]], 1);
}

__global__ __launch_bounds__(256) void scan_partial_kernel(
    const int* __restrict__ deg, int* __restrict__ bsum)
{
    __shared__ int s[256];
    int t = threadIdx.x;
    int i = blockIdx.x * 256 + t;
    s[t] = (i < NN) ? deg[i] : 0;
    __syncthreads();
    #pragma unroll
    for (int o = 128; o > 0; o >>= 1) {
        if (t < o) s[t] += s[t + o];
        __syncthreads();
    }
    if (t == 0) bsum[blockIdx.x] = s[0];
}

__global__ __launch_bounds__(256) void scan_tot_kernel(
    int* __restrict__ bsum, int* __restrict__ offsets)
{
    __shared__ int s[256];
    int t = threadIdx.x;
    int v = (t < NBLK_SCAN) ? bsum[t] : 0;
    s[t] = v;
    __syncthreads();
    for (int o = 1; o < 256; o <<= 1) {
        int add = (t >= o) ? s[t - o] : 0;
        __syncthreads();
        s[t] += add;
        __syncthreads();
    }
    if (t < NBLK_SCAN) bsum[t] = s[t] - v;
    if (t == 255) offsets[NN] = s[255];
}

__global__ __launch_bounds__(256) void scan_final_kernel(
    int* deg, const int* __restrict__ bsum, int* __restrict__ offsets)
{
    __shared__ int s[256];
    int t = threadIdx.x;
    int i = blockIdx.x * 256 + t;
    int v = (i < NN) ? deg[i] : 0;
    s[t] = v;
    __syncthreads();
    for (int o = 1; o < 256; o <<= 1) {
        int add = (t >= o) ? s[t - o] : 0;
        __syncthreads();
        s[t] += add;
        __syncthreads();
    }
    int excl = s[t] - v + bsum[blockIdx.x];
    if (i < NN) offsets[i] = excl;
}

// bucket cursors for the binning pass: bcur[b] = offs[128b]
__global__ __launch_bounds__(256) void init_bcur_kernel(
    const int* __restrict__ offs, int* __restrict__ bcur)
{
    int b = blockIdx.x * 256 + threadIdx.x;
    if (b < NBUCKET) bcur[b] = offs[b * 128];
}

// ---------------- pass 1: bin edges by bucket (coalesced-run writes) ------
__global__ __launch_bounds__(256) void bucket_bin_kernel(
    const int* __restrict__ row, const int* __restrict__ col,
    const float* __restrict__ val, int* __restrict__ bcur,
    int2* __restrict__ ebin)
{
    __shared__ int lh[NBUCKET];
    __shared__ int lg[NBUCKET];
    int tid = threadIdx.x;
    for (int i = tid; i < NBUCKET; i += 256) lh[i] = 0;
    __syncthreads();
    int base = blockIdx.x * 2048;
    int eb[8], er[8], ec[8], ev[8];
    #pragma unroll
    for (int j = 0; j < 8; ++j) {
        int e = base + j * 256 + tid;
        eb[j] = -1;
        if (e < EE) {
            int r = row[e];
            int b = r >> 7;
            eb[j] = b;
            er[j] = atomicAdd(&lh[b], 1);              // local rank
            ec[j] = col[e] | ((r & 127) << 17);        // col(17b) | rowlocal(7b)
            ev[j] = __float_as_int(val[e]);
        }
    }
    __syncthreads();
    for (int i = tid; i < NBUCKET; i += 256)
        if (lh[i]) lg[i] = atomicAdd(&bcur[i], lh[i]);
    __syncthreads();
    #pragma unroll
    for (int j = 0; j < 8; ++j) {
        if (eb[j] >= 0)
            ebin[lg[eb[j]] + er[j]] = make_int2(ec[j], ev[j]);
    }
}

// ---------------- pass 2: row-sort within bucket (16 KB window writes) ----
__global__ __launch_bounds__(256) void rebin_kernel(
    const int* __restrict__ offs, const int2* __restrict__ ebin,
    int2* __restrict__ epack)
{
    __shared__ int lcur[128];
    int b = blockIdx.x;
    int tid = threadIdx.x;
    int rbase = b * 128;
    if (tid < 128) {
        int r = rbase + tid;
        lcur[tid] = (r < NN) ? offs[r] : 0;
    }
    __syncthreads();
    int beg = offs[rbase];
    int end = offs[min(rbase + 128, NN)];
    for (int e = beg + tid; e < end; e += 256) {
        int2 ed = ebin[e];
        int rl = ed.x >> 17;                 // rowlocal (bits 17..23, positive)
        int p = atomicAdd(&lcur[rl], 1);
        epack[p] = make_int2(ed.x & 0x1FFFF, ed.y);
    }
}

// ---------------- gather-aggregate (row CSR, bf16 x) -> bf16 agg ----------
__global__ __launch_bounds__(256) void gather_kernel(
    const unsigned short* __restrict__ xb, const int* __restrict__ offsets,
    const int2* __restrict__ epack, const float* __restrict__ epsp,
    unsigned short* __restrict__ aggb)
{
    int rid = blockIdx.x * 8 + (threadIdx.x >> 5);
    if (rid >= NN) return;
    int lane = threadIdx.x & 31;
    int beg = offsets[rid], end = offsets[rid + 1];
    float a0 = 0.f, a1 = 0.f, a2 = 0.f;
    int j = beg;
    for (; j + 4 <= end; j += 4) {
        int2 e0 = epack[j],   e1 = epack[j+1];
        int2 e2 = epack[j+2], e3 = epack[j+3];
        const unsigned short* x0 = xb + (size_t)e0.x * FIN;
        const unsigned short* x1 = xb + (size_t)e1.x * FIN;
        const unsigned short* x2 = xb + (size_t)e2.x * FIN;
        const unsigned short* x3 = xb + (size_t)e3.x * FIN;
        float v0 = __int_as_float(e0.y), v1 = __int_as_float(e1.y);
        float v2 = __int_as_float(e2.y), v3 = __int_as_float(e3.y);
        a0 += v0*b2f(x0[lane])    + v1*b2f(x1[lane])
            + v2*b2f(x2[lane])    + v3*b2f(x3[lane]);
        a1 += v0*b2f(x0[lane+32]) + v1*b2f(x1[lane+32])
            + v2*b2f(x2[lane+32]) + v3*b2f(x3[lane+32]);
        a2 += v0*b2f(x0[lane+64]) + v1*b2f(x1[lane+64])
            + v2*b2f(x2[lane+64]) + v3*b2f(x3[lane+64]);
    }
    for (; j < end; ++j) {
        int2 e = epack[j];
        float v = __int_as_float(e.y);
        const unsigned short* xr = xb + (size_t)e.x * FIN;
        a0 += v * b2f(xr[lane]);
        a1 += v * b2f(xr[lane + 32]);
        a2 += v * b2f(xr[lane + 64]);
    }
    float e = epsp[0];
    const unsigned short* xs = xb + (size_t)rid * FIN;
    a0 += e * b2f(xs[lane]);
    a1 += e * b2f(xs[lane + 32]);
    a2 += e * b2f(xs[lane + 64]);
    unsigned short* ar = aggb + (size_t)rid * FIN;
    ar[lane]      = f2b(a0);
    ar[lane + 32] = f2b(a1);
    ar[lane + 64] = f2b(a2);
}

// ---------------- GEMM1 (MFMA): h1 = agg @ W1 + b1, bf16 out + stats -----
__global__ __launch_bounds__(256) void gemm1_mfma_kernel(
    const unsigned short* __restrict__ aggb, const unsigned short* __restrict__ W1T,
    const float* __restrict__ b1,
    unsigned short* __restrict__ h1, float* __restrict__ sum1,
    float* __restrict__ sq1)
{
    __shared__ short As[128 * 104];   // [m][k] bf16
    __shared__ short Bs[128 * 104];   // [n][k] bf16
    int tid = threadIdx.x;
    int m0 = blockIdx.x * 128;
    int n0 = blockIdx.y * 128;
    int lane = tid & 63;
    int w = tid >> 6, wr = w >> 1, wc = w & 1;
    int l15 = lane & 15, lk = (lane >> 4) * 8;

    for (int i8 = tid; i8 < 128 * 12; i8 += 256) {
        int m = i8 / 12;
        int k8 = (i8 - m * 12) * 8;
        int gm = m0 + m;
        short8v v = (short8v)(short)0;
        if (gm < NN) v = *(const short8v*)(aggb + (size_t)gm * FIN + k8);
        *(short8v*)&As[m * 104 + k8] = v;
    }
    for (int i8 = tid; i8 < 128 * 12; i8 += 256) {
        int n = i8 / 12;
        int k8 = (i8 - n * 12) * 8;
        *(short8v*)&Bs[n * 104 + k8] =
            *(const short8v*)(W1T + (size_t)(n0 + n) * FIN + k8);
    }
    __syncthreads();

    f32x4 acc[4][4];
    #pragma unroll
    for (int a = 0; a < 4; ++a)
        #pragma unroll
        for (int b = 0; b < 4; ++b) acc[a][b] = (f32x4)(0.f);

    #pragma unroll
    for (int ks = 0; ks < 3; ++ks) {
        int k0 = ks * 32;
        short8v af[4], bf[4];
        #pragma unroll
        for (int f = 0; f < 4; ++f)
            af[f] = *(short8v*)&As[(wr*64 + f*16 + l15) * 104 + k0 + lk];
        #pragma unroll
        for (int f = 0; f < 4; ++f)
            bf[f] = *(short8v*)&Bs[(wc*64 + f*16 + l15) * 104 + k0 + lk];
        #pragma unroll
        for (int fm = 0; fm < 4; ++fm)
            #pragma unroll
            for (int fn = 0; fn < 4; ++fn)
                acc[fm][fn] = __builtin_amdgcn_mfma_f32_16x16x32_bf16(
                    af[fm], bf[fn], acc[fm][fn], 0, 0, 0);
    }

    float bias[4], cs[4], cq[4];
    #pragma unroll
    for (int fn = 0; fn < 4; ++fn) {
        bias[fn] = b1[n0 + wc*64 + fn*16 + l15];
        cs[fn] = 0.f; cq[fn] = 0.f;
    }
    #pragma unroll
    for (int fm = 0; fm < 4; ++fm) {
        int mb = m0 + wr*64 + fm*16 + (lane >> 4) * 4;
        #pragma unroll
        for (int r = 0; r < 4; ++r) {
            int gm = mb + r;
            if (gm < NN) {
                #pragma unroll
                for (int fn = 0; fn < 4; ++fn) {
                    float h = acc[fm][fn][r] + bias[fn];
                    cs[fn] += h; cq[fn] += h * h;
                    h1[(size_t)gm * FHID + n0 + wc*64 + fn*16 + l15] = f2b(h);
                }
            }
        }
    }
    #pragma unroll
    for (int fn = 0; fn < 4; ++fn) {
        cs[fn] += __shfl_xor(cs[fn], 16); cs[fn] += __shfl_xor(cs[fn], 32);
        cq[fn] += __shfl_xor(cq[fn], 16); cq[fn] += __shfl_xor(cq[fn], 32);
    }
    __syncthreads();
    float* sS = (float*)As;
    if (lane < 16) {
        #pragma unroll
        for (int fn = 0; fn < 4; ++fn) {
            sS[w * 64 + fn * 16 + l15]       = cs[fn];
            sS[256 + w * 64 + fn * 16 + l15] = cq[fn];
        }
    }
    __syncthreads();
    if (tid < 128) {
        float s = sS[tid] + sS[tid + 128];
        float q = sS[256 + tid] + sS[256 + tid + 128];
        atomicAdd(sum1 + n0 + tid, s);
        atomicAdd(sq1 + n0 + tid, q);
    }
}

// ---- fold BN stats into scale/shift --------------------------------------
__global__ __launch_bounds__(256) void bnparam_kernel(
    const float* __restrict__ sum, const float* __restrict__ sq,
    const float* __restrict__ g, const float* __restrict__ be,
    float* __restrict__ scale, float* __restrict__ shift, int F)
{
    int i = blockIdx.x * 256 + threadIdx.x;
    if (i >= F) return;
    float mean = sum[i] * (1.f / NN);
    float var  = sq[i] * (1.f / NN) - mean * mean;
    float s = g[i] * rsqrtf(var + BN_EPS);
    scale[i] = s;
    shift[i] = be[i] - mean * s;
}

// ---------------- GEMM2 (MFMA): out = elu(bn1(h1)) @ W2 + b2, + stats ----
#define G2_LDA 72
#define G2_LDB 72
__global__ __launch_bounds__(256) void gemm2_mfma_kernel(
    const unsigned short* __restrict__ h1, const unsigned short* __restrict__ W2T,
    const float* __restrict__ b2,
    const float* __restrict__ scale1, const float* __restrict__ shift1,
    float* __restrict__ out, float* __restrict__ sum2, float* __restrict__ sq2)
{
    __shared__ short As[64 * G2_LDA];
    __shared__ short Bs[192 * G2_LDB];
    __shared__ float sc[FHID], sh[FHID];
    int tid = threadIdx.x;
    int m0 = blockIdx.x * 64;
    int lane = tid & 63;
    int w = tid >> 6, wr = w >> 1, wc = w & 1;
    int l15 = lane & 15, lk = (lane >> 4) * 8;

    for (int i = tid; i < FHID; i += 256) { sc[i] = scale1[i]; sh[i] = shift1[i]; }

    short8v pa[2], pb[6];

    auto LOAD = [&](int k0) {
        #pragma unroll
        for (int l = 0; l < 2; ++l) {
            int idx = tid + l * 256;
            int am = idx >> 3, k8 = (idx & 7) * 8;
            int gm = m0 + am;
            pa[l] = (gm < NN)
                ? *(const short8v*)(h1 + (size_t)gm * FHID + k0 + k8)
                : (short8v)(short)0;
        }
        #pragma unroll
        for (int l = 0; l < 6; ++l) {
            int idx = tid + l * 256;
            int bn = idx >> 3, k8 = (idx & 7) * 8;
            pb[l] = *(const short8v*)(W2T + (size_t)bn * FHID + k0 + k8);
        }
    };
    auto WRITE = [&](int k0) {
        #pragma unroll
        for (int l = 0; l < 2; ++l) {
            int idx = tid + l * 256;
            int am = idx >> 3, k8 = (idx & 7) * 8;
            short8v v;
            #pragma unroll
            for (int j = 0; j < 8; ++j) {
                int k = k0 + k8 + j;
                float t = sc[k] * b2f((unsigned short)pa[l][j]) + sh[k];
                float e = t > 0.f ? t : __expf(t) - 1.f;
                v[j] = (short)f2b(e);
            }
            *(short8v*)&As[am * G2_LDA + k8] = v;
        }
        #pragma unroll
        for (int l = 0; l < 6; ++l) {
            int idx = tid + l * 256;
            int bn = idx >> 3, k8 = (idx & 7) * 8;
            *(short8v*)&Bs[bn * G2_LDB + k8] = pb[l];
        }
    };

    f32x4 acc[2][6];
    #pragma unroll
    for (int a = 0; a < 2; ++a)
        #pragma unroll
        for (int b = 0; b < 6; ++b) acc[a][b] = (f32x4)(0.f);

    LOAD(0);
    __syncthreads();
    WRITE(0);
    __syncthreads();

    for (int t = 0; t < 6; ++t) {
        if (t < 5) LOAD((t + 1) * 64);
        #pragma unroll
        for (int ks = 0; ks < 2; ++ks) {
            short8v af[2], bf[6];
            #pragma unroll
            for (int f = 0; f < 2; ++f)
                af[f] = *(short8v*)&As[(wr*32 + f*16 + l15) * G2_LDA + ks*32 + lk];
            #pragma unroll
            for (int g = 0; g < 6; ++g)
                bf[g] = *(short8v*)&Bs[(wc*96 + g*16 + l15) * G2_LDB + ks*32 + lk];
            #pragma unroll
            for (int fm = 0; fm < 2; ++fm)
                #pragma unroll
                for (int fn = 0; fn < 6; ++fn)
                    acc[fm][fn] = __builtin_amdgcn_mfma_f32_16x16x32_bf16(
                        af[fm], bf[fn], acc[fm][fn], 0, 0, 0);
        }
        __syncthreads();
        if (t < 5) {
            WRITE((t + 1) * 64);
            __syncthreads();
        }
    }

    float bias[6], cs[6], cq[6];
    #pragma unroll
    for (int fn = 0; fn < 6; ++fn) {
        bias[fn] = b2[wc*96 + fn*16 + l15];
        cs[fn] = 0.f; cq[fn] = 0.f;
    }
    #pragma unroll
    for (int fm = 0; fm < 2; ++fm) {
        int mb = m0 + wr*32 + fm*16 + (lane >> 4) * 4;
        #pragma unroll
        for (int r = 0; r < 4; ++r) {
            int gm = mb + r;
            if (gm < NN) {
                #pragma unroll
                for (int fn = 0; fn < 6; ++fn) {
                    float v = acc[fm][fn][r] + bias[fn];
                    cs[fn] += v; cq[fn] += v * v;
                    out[(size_t)gm * FOUT + wc*96 + fn*16 + l15] = v;
                }
            }
        }
    }
    #pragma unroll
    for (int fn = 0; fn < 6; ++fn) {
        cs[fn] += __shfl_xor(cs[fn], 16); cs[fn] += __shfl_xor(cs[fn], 32);
        cq[fn] += __shfl_xor(cq[fn], 16); cq[fn] += __shfl_xor(cq[fn], 32);
    }
    __syncthreads();
    float* sS = (float*)As;
    if (lane < 16) {
        #pragma unroll
        for (int fn = 0; fn < 6; ++fn) {
            sS[w * 96 + fn * 16 + l15]       = cs[fn];
            sS[384 + w * 96 + fn * 16 + l15] = cq[fn];
        }
    }
    __syncthreads();
    if (tid < 192) {
        float s = sS[tid] + sS[192 + tid];
        float q = sS[384 + tid] + sS[384 + 192 + tid];
        atomicAdd(sum2 + tid, s);
        atomicAdd(sq2 + tid, q);
    }
}

// ---------------- BN2 + ELU, in-place ------------------------------------
__global__ __launch_bounds__(256) void bn2_elu_kernel(
    float* __restrict__ out, const float* __restrict__ scale2,
    const float* __restrict__ shift2)
{
    int gid = blockIdx.x * 256 + threadIdx.x;
    if (gid >= NN * FOUT / 4) return;
    size_t base = (size_t)gid * 4;
    int c0 = (int)(base % FOUT);
    float4 h = *(float4*)(out + base);
    float hv[4] = {h.x, h.y, h.z, h.w};
    float rv[4];
    #pragma unroll
    for (int j = 0; j < 4; ++j) {
        float t = scale2[c0 + j] * hv[j] + shift2[c0 + j];
        rv[j] = t > 0.f ? t : __expf(t) - 1.f;
    }
    *(float4*)(out + base) = make_float4(rv[0], rv[1], rv[2], rv[3]);
}

__global__ __launch_bounds__(256) void zero_out_kernel(float* out, int n) {
    int gid = blockIdx.x * 256 + threadIdx.x;
    if (gid < n) out[gid] = 0.f;
}

extern "C" void kernel_launch(void* const* d_in, const int* in_sizes, int n_in,
                              void* d_out, int out_size, void* d_ws, size_t ws_size,
                              hipStream_t stream) {
    const float* x    = (const float*)d_in[0];
    const float* val  = (const float*)d_in[1];
    const float* W1   = (const float*)d_in[2];
    const float* b1   = (const float*)d_in[3];
    const float* g1   = (const float*)d_in[4];
    const float* be1  = (const float*)d_in[5];
    const float* W2   = (const float*)d_in[6];
    const float* b2   = (const float*)d_in[7];
    const float* g2   = (const float*)d_in[8];
    const float* be2  = (const float*)d_in[9];
    const float* epsp = (const float*)d_in[10];
    const int* row    = (const int*)d_in[11];
    const int* col    = (const int*)d_in[12];
    float* out = (float*)d_out;

    // ws layout (float idx):
    //       0 stats/scale/shift [2304]
    //    2304 deg int[50000]          -> 52304
    //   52304 offs int[50001]         -> 102305
    //  102305 bsum int[256]           -> 102561
    //  102561 bcur int[391]           -> 102952 (pad to 102960)
    //  102960 W1T ushort[36864]       (18432 f) -> 121392
    //  121392 W2T ushort[73728]       (36864 f) -> 158256
    //  158256 xb  ushort[4.8M]        (2.4M f)  -> 2558256
    // 2558256 aggb ushort[4.8M]       (2.4M f)  -> 4958256 ; ebin int2[800K]
    //         aliases this region (dead before gather writes aggb)
    // 4958256 h1 bf16[19.2M]          (9.6M f)  -> 14558256 ; epack int2[800K]
    //         aliases h1 (dead before gemm1 writes h1)
    const size_t need = (size_t)14558256 * sizeof(float);
    if (ws_size < need) {
        zero_out_kernel<<<(out_size + 255) / 256, 256, 0, stream>>>(out, out_size);
        return;
    }
    float* ws     = (float*)d_ws;
    float* sum1   = ws;
    float* sq1    = ws + 384;
    float* sum2   = ws + 768;
    float* sq2    = ws + 960;
    float* scale1 = ws + 1152;
    float* shift1 = ws + 1536;
    float* scale2 = ws + 1920;
    float* shift2 = ws + 2112;
    int*   deg    = (int*)(ws + 2304);
    int*   offs   = (int*)(ws + 52304);
    int*   bsum   = (int*)(ws + 102305);
    int*   bcur   = (int*)(ws + 102561);
    unsigned short* W1T  = (unsigned short*)(ws + 102960);
    unsigned short* W2T  = (unsigned short*)(ws + 121392);
    unsigned short* xb   = (unsigned short*)(ws + 158256);
    unsigned short* aggb = (unsigned short*)(ws + 2558256);
    int2*  ebin   = (int2*)(ws + 2558256);          // alias aggb (dead early)
    unsigned short* h1   = (unsigned short*)(ws + 4958256);
    int2*  epack  = (int2*)(ws + 4958256);          // alias h1 (dead early)

    // zero stats + deg (209 KB)
    hipMemsetAsync(d_ws, 0, 52304 * sizeof(float), stream);

    prep_w_kernel<<<(FHID*FIN + FOUT*FHID + 255) / 256, 256, 0, stream>>>(
        W1, W2, W1T, W2T);
    prep_x_kernel<<<(NN * FIN / 4 + 255) / 256, 256, 0, stream>>>(x, xb);

    hist_kernel<<<(EE + 255) / 256, 256, 0, stream>>>(row, deg);
    scan_partial_kernel<<<NBLK_SCAN, 256, 0, stream>>>(deg, bsum);
    scan_tot_kernel<<<1, 256, 0, stream>>>(bsum, offs);
    scan_final_kernel<<<NBLK_SCAN, 256, 0, stream>>>(deg, bsum, offs);
    init_bcur_kernel<<<2, 256, 0, stream>>>(offs, bcur);

    bucket_bin_kernel<<<NCHUNK, 256, 0, stream>>>(row, col, val, bcur, ebin);
    rebin_kernel<<<NBUCKET, 256, 0, stream>>>(offs, ebin, epack);
    gather_kernel<<<(NN + 7) / 8, 256, 0, stream>>>(xb, offs, epack, epsp, aggb);

    dim3 grid1((NN + 127) / 128, 3, 1);
    gemm1_mfma_kernel<<<grid1, 256, 0, stream>>>(aggb, W1T, b1, h1, sum1, sq1);
    bnparam_kernel<<<2, 256, 0, stream>>>(sum1, sq1, g1, be1, scale1, shift1, FHID);

    gemm2_mfma_kernel<<<(NN + 63) / 64, 256, 0, stream>>>(
        h1, W2T, b2, scale1, shift1, out, sum2, sq2);
    bnparam_kernel<<<1, 256, 0, stream>>>(sum2, sq2, g2, be2, scale2, shift2, FOUT);

    bn2_elu_kernel<<<(NN * FOUT / 4 + 255) / 256, 256, 0, stream>>>(
        out, scale2, shift2);
}